// Round 9
// baseline (254.562 us; speedup 1.0000x reference)
//
#include <hip/hip_runtime.h>

#define N_NODES 100000
#define N_EDGES 1600000
#define C 128
#define LEAKY 0.01f
#define BN_EPS 1e-5f
#define NB_C 391           // coarse buckets (dst>>8), 256 nodes each
#define PB 391             // partition blocks
#define PBLK 4096          // edges per partition block
#define STASH 8192         // fine-kernel LDS pair stash (avg bucket = 4092)
#define NBG 1563           // gemm blocks = ceil(100000/64)

typedef __attribute__((ext_vector_type(8))) short short8;   // 8 bf16 = 16B
typedef __attribute__((ext_vector_type(4))) float f32x4;

__device__ __forceinline__ unsigned short f2bf(float f) {   // RNE float->bf16
    unsigned int u = __builtin_bit_cast(unsigned int, f);
    u += 0x7FFFu + ((u >> 16) & 1u);
    return (unsigned short)(u >> 16);
}
__device__ __forceinline__ float bf2f(unsigned short b) {
    unsigned int u = ((unsigned int)b) << 16;
    return __builtin_bit_cast(float, u);
}

// ---------------------------------------------------------------- init: cast-transpose W
__global__ __launch_bounds__(256) void k_init(const float* __restrict__ W,
                                              unsigned short* __restrict__ wt) {
    int i = blockIdx.x * 256 + threadIdx.x;
    wt[i] = f2bf(W[(i & 127) * C + (i >> 7)]);   // wt[c][k] = W[k][c]
}

// ---------------------------------------------------------------- coarse histogram: per-block counts per bucket
__global__ __launch_bounds__(256) void k_coarse(const int* __restrict__ dst,
                                                int* __restrict__ blk_cnt) {
    __shared__ int lh[NB_C];
    int tid = threadIdx.x, blk = blockIdx.x;
    for (int i = tid; i < NB_C; i += 256) lh[i] = 0;
    __syncthreads();
    #pragma unroll
    for (int it = 0; it < PBLK / 256; ++it) {
        int e = blk * PBLK + it * 256 + tid;
        if (e < N_EDGES) atomicAdd(&lh[dst[e] >> 8], 1);
    }
    __syncthreads();
    for (int i = tid; i < NB_C; i += 256) blk_cnt[i * PB + blk] = lh[i];
}

// ---------------------------------------------------------------- per-bucket exclusive scan over blocks
__global__ __launch_bounds__(512) void k_offsets(const int* __restrict__ blk_cnt,
                                                 int* __restrict__ offset,
                                                 int* __restrict__ total) {
    __shared__ int tmp[512];
    int t = threadIdx.x, k = blockIdx.x;
    int v = (t < PB) ? blk_cnt[k * PB + t] : 0;
    tmp[t] = v;
    __syncthreads();
    for (int off = 1; off < 512; off <<= 1) {
        int u = (t >= off) ? tmp[t - off] : 0;
        __syncthreads();
        tmp[t] += u;
        __syncthreads();
    }
    if (t < PB) offset[k * PB + t] = tmp[t] - v;
    if (t == 511) total[k] = tmp[511];
}

// ---------------------------------------------------------------- bucket-base scan (1 block)
__global__ __launch_bounds__(512) void k_cbase(const int* __restrict__ total,
                                               int* __restrict__ cbase,
                                               int* __restrict__ offs) {
    __shared__ int tmp[512];
    int t = threadIdx.x;
    int v = (t < NB_C) ? total[t] : 0;
    tmp[t] = v;
    __syncthreads();
    for (int off = 1; off < 512; off <<= 1) {
        int u = (t >= off) ? tmp[t - off] : 0;
        __syncthreads();
        tmp[t] += u;
        __syncthreads();
    }
    if (t < NB_C) cbase[t] = tmp[t] - v;
    if (t == 0) { cbase[NB_C] = N_EDGES; offs[N_NODES] = N_EDGES; }
}

// ---------------------------------------------------------------- partition: packed (src | dlow<<17) into bucket chunks
__global__ __launch_bounds__(256) void k_partition(const int* __restrict__ src,
                                                   const int* __restrict__ dst,
                                                   const int* __restrict__ cbase,
                                                   const int* __restrict__ offset,
                                                   unsigned int* __restrict__ pairs) {
    __shared__ int lh[NB_C];
    __shared__ int lbase[NB_C];
    int tid = threadIdx.x, blk = blockIdx.x;
    for (int i = tid; i < NB_C; i += 256) {
        lh[i] = 0;
        lbase[i] = cbase[i] + offset[i * PB + blk];
    }
    __syncthreads();
    #pragma unroll
    for (int it = 0; it < PBLK / 256; ++it) {
        int e = blk * PBLK + it * 256 + tid;
        if (e < N_EDGES) {
            int d = dst[e];
            int b = d >> 8;
            int r = atomicAdd(&lh[b], 1);
            pairs[lbase[b] + r] = (unsigned int)src[e] | ((unsigned int)(d & 255) << 17);
        }
    }
}

// ---------------------------------------------------------------- fine: hist -> dinv+offs; LDS-rank -> srt; cast xb=x*dinv
__global__ __launch_bounds__(256) void k_fine(const unsigned int* __restrict__ pairs,
                                              const int* __restrict__ cbase,
                                              const float* __restrict__ x,
                                              float* __restrict__ dinv,
                                              int* __restrict__ offs,
                                              int* __restrict__ srt,
                                              unsigned short* __restrict__ xb) {
    __shared__ int hist[256];
    __shared__ int loff[256];
    __shared__ int cnt2[256];
    __shared__ unsigned int stash[STASH];
    int tid = threadIdx.x, blk = blockIdx.x;
    int nbase = blk * 256;
    int nn = (nbase + 256 <= N_NODES) ? 256 : (N_NODES - nbase);
    int ebeg = cbase[blk];
    int ne = cbase[blk + 1] - ebeg;

    hist[tid] = 0; cnt2[tid] = 0;
    __syncthreads();
    for (int k = tid; k < ne; k += 256) {
        unsigned int pk = pairs[ebeg + k];
        if (k < STASH) stash[k] = pk;
        atomicAdd(&hist[pk >> 17], 1);
    }
    __syncthreads();
    if (tid < nn) dinv[nbase + tid] = rsqrtf((float)(hist[tid] + 1));
    // exclusive scan of hist into loff
    loff[tid] = hist[tid];
    __syncthreads();
    for (int off = 1; off < 256; off <<= 1) {
        int u = (tid >= off) ? loff[tid - off] : 0;
        __syncthreads();
        loff[tid] += u;
        __syncthreads();
    }
    loff[tid] -= hist[tid];           // exclusive
    if (tid < nn) offs[nbase + tid] = ebeg + loff[tid];
    __syncthreads();
    for (int k = tid; k < ne; k += 256) {
        unsigned int pk = (k < STASH) ? stash[k] : pairs[ebeg + k];
        int dl = pk >> 17;
        int r = atomicAdd(&cnt2[dl], 1);
        srt[ebeg + loff[dl] + r] = (int)(pk & 0x1FFFFu);
    }
    // cast this bucket's x rows: xb[n] = bf16(x[n] * dinv[n])
    for (int t = tid; t < nn * 32; t += 256) {
        int r = t >> 5, c4 = t & 31;
        float dv = rsqrtf((float)(hist[r] + 1));
        size_t q = ((size_t)(nbase + r) << 5) + c4;   // float4 index
        float4 xv = ((const float4*)x)[q];
        ushort4 o;
        o.x = f2bf(xv.x * dv); o.y = f2bf(xv.y * dv);
        o.z = f2bf(xv.z * dv); o.w = f2bf(xv.w * dv);
        ((ushort4*)xb)[q] = o;
    }
}

// ---------------------------------------------------------------- aggregate: agg[d] = bf16( dn * (xb[d] + sum xb[s]) )
__global__ __launch_bounds__(256) void k_aggregate(const ushort4* __restrict__ xb4,
                                                   const int* __restrict__ srt,
                                                   const int* __restrict__ offs,
                                                   const float* __restrict__ dinv,
                                                   unsigned long long* __restrict__ agg8) {
    int node = blockIdx.x * 8 + (threadIdx.x >> 5);
    int lane = threadIdx.x & 31;

    float dn = dinv[node];
    int beg = offs[node];
    int end = offs[node + 1];

    ushort4 ms = xb4[(size_t)node * 32 + lane];
    float ax = bf2f(ms.x), ay = bf2f(ms.y), az = bf2f(ms.z), aw = bf2f(ms.w);

    int k = beg;
    for (; k + 8 <= end; k += 8) {      // unmasked 8-wide MLP batch
        int idx[8];
        #pragma unroll
        for (int i = 0; i < 8; ++i) idx[i] = __builtin_nontemporal_load(&srt[k + i]);
        ushort4 m[8];
        #pragma unroll
        for (int i = 0; i < 8; ++i) m[i] = xb4[(size_t)idx[i] * 32 + lane];
        #pragma unroll
        for (int i = 0; i < 8; ++i) {
            ax += bf2f(m[i].x); ay += bf2f(m[i].y);
            az += bf2f(m[i].z); aw += bf2f(m[i].w);
        }
    }
    for (; k < end; ++k) {              // scalar tail (<8 iters)
        int s = __builtin_nontemporal_load(&srt[k]);
        ushort4 m = xb4[(size_t)s * 32 + lane];
        ax += bf2f(m.x); ay += bf2f(m.y); az += bf2f(m.z); aw += bf2f(m.w);
    }

    ushort4 o;
    o.x = f2bf(dn * ax); o.y = f2bf(dn * ay);
    o.z = f2bf(dn * az); o.w = f2bf(dn * aw);
    unsigned long long packed = __builtin_bit_cast(unsigned long long, o);
    __builtin_nontemporal_store(packed, &agg8[(size_t)node * 32 + lane]);
}

// ---------------------------------------------------------------- gemm: out = leaky(agg@W + bias), + BN partials
__global__ __launch_bounds__(256) void k_gemm(const unsigned short* __restrict__ agg,
                                              const unsigned short* __restrict__ wt,
                                              const float* __restrict__ bias,
                                              float* __restrict__ out,
                                              float* __restrict__ part) {
    __shared__ float lsum[C], lsq[C];
    for (int i = threadIdx.x; i < C; i += 256) { lsum[i] = 0.0f; lsq[i] = 0.0f; }
    __syncthreads();

    int tile = blockIdx.x * 4 + (threadIdx.x >> 6);
    int lane = threadIdx.x & 63;
    if (tile < N_NODES / 16) {
        int row0 = tile * 16;
        int ar = lane & 15;
        int kg = (lane >> 4) * 8;

        short8 a[4];
        #pragma unroll
        for (int kk = 0; kk < 4; ++kk)
            a[kk] = *(const short8*)&agg[(size_t)(row0 + ar) * C + kk * 32 + kg];

        int rb = (lane >> 4) * 4;
        #pragma unroll
        for (int ct = 0; ct < 8; ++ct) {
            f32x4 acc = {0.f, 0.f, 0.f, 0.f};
            #pragma unroll
            for (int kk = 0; kk < 4; ++kk) {
                short8 b = *(const short8*)&wt[(size_t)(ct * 16 + ar) * C + kk * 32 + kg];
                acc = __builtin_amdgcn_mfma_f32_16x16x32_bf16(a[kk], b, acc, 0, 0, 0);
            }
            int col = ct * 16 + ar;      // C/D: col=lane&15, row=(lane>>4)*4+r
            float bb = bias[col];
            float s = 0.0f, q = 0.0f;
            #pragma unroll
            for (int r = 0; r < 4; ++r) {
                float v = acc[r] + bb;
                v = v > 0.0f ? v : LEAKY * v;
                out[(size_t)(row0 + rb + r) * C + col] = v;
                s += v; q += v * v;
            }
            atomicAdd(&lsum[col], s);
            atomicAdd(&lsq[col], q);
        }
    }
    __syncthreads();
    for (int i = threadIdx.x; i < C; i += 256) {
        part[(size_t)blockIdx.x * 256 + i]       = lsum[i];
        part[(size_t)blockIdx.x * 256 + 128 + i] = lsq[i];
    }
}

// ---------------------------------------------------------------- params: reduce partials, fold BN scale/shift
__global__ __launch_bounds__(1024) void k_params(const float* __restrict__ part,
                                                 const float* __restrict__ gamma,
                                                 const float* __restrict__ beta,
                                                 float* __restrict__ scale,
                                                 float* __restrict__ shift) {
    __shared__ float rs[1024], rq[1024];
    int c = threadIdx.x & 127, g = threadIdx.x >> 7;   // 8 groups
    float s = 0.0f, q = 0.0f;
    for (int b = g; b < NBG; b += 8) {
        s += part[(size_t)b * 256 + c];
        q += part[(size_t)b * 256 + 128 + c];
    }
    rs[threadIdx.x] = s; rq[threadIdx.x] = q;
    __syncthreads();
    if (threadIdx.x < 128) {
        float S = 0.0f, Q = 0.0f;
        #pragma unroll
        for (int g2 = 0; g2 < 8; ++g2) { S += rs[g2 * 128 + c]; Q += rq[g2 * 128 + c]; }
        float inv_n = 1.0f / (float)N_NODES;
        float mean = S * inv_n;
        float var = Q * inv_n - mean * mean;
        float sc = gamma[c] * rsqrtf(var + BN_EPS);
        scale[c] = sc;
        shift[c] = beta[c] - mean * sc;
    }
}

// ---------------------------------------------------------------- apply: out = out*scale + shift (in place)
__global__ __launch_bounds__(256) void k_apply(float* __restrict__ out,
                                               const float* __restrict__ scale,
                                               const float* __restrict__ shift) {
    int i = blockIdx.x * 256 + threadIdx.x;  // float4 index, exactly N*C/4
    int c4 = i & 31;
    float4 v = ((float4*)out)[i];
    float4 sc = ((const float4*)scale)[c4];
    float4 sh = ((const float4*)shift)[c4];
    v.x = v.x * sc.x + sh.x;
    v.y = v.y * sc.y + sh.y;
    v.z = v.z * sc.z + sh.z;
    v.w = v.w * sc.w + sh.w;
    ((float4*)out)[i] = v;
}

extern "C" void kernel_launch(void* const* d_in, const int* in_sizes, int n_in,
                              void* d_out, int out_size, void* d_ws, size_t ws_size,
                              hipStream_t stream) {
    const float* x     = (const float*)d_in[0];
    const int*   edge  = (const int*)d_in[1];
    const float* W     = (const float*)d_in[2];
    const float* bias  = (const float*)d_in[3];
    const float* gamma = (const float*)d_in[4];
    const float* beta  = (const float*)d_in[5];
    float* out = (float*)d_out;
    char* ws = (char*)d_ws;

    // workspace layout (~68 MB)
    unsigned short* xb    = (unsigned short*)ws;  ws += (size_t)N_NODES * C * 2;   // 25.6 MB
    unsigned short* agg   = (unsigned short*)ws;  ws += (size_t)N_NODES * C * 2;   // 25.6 MB
    unsigned short* wt    = (unsigned short*)ws;  ws += (size_t)C * C * 2;         // 32 KB
    unsigned int*   pairs = (unsigned int*)ws;    ws += (size_t)N_EDGES * 4;       // 6.4 MB
    int*   srt     = (int*)ws;                    ws += (size_t)N_EDGES * 4;       // 6.4 MB
    int*   blk_cnt = (int*)ws;                    ws += (size_t)NB_C * PB * 4;     // 612 KB
    int*   offset  = (int*)ws;                    ws += (size_t)NB_C * PB * 4;     // 612 KB
    int*   total   = (int*)ws;                    ws += 512 * 4;
    int*   cbase   = (int*)ws;                    ws += 512 * 4;
    int*   offs    = (int*)ws;                    ws += (size_t)(N_NODES + 1) * 4; // 400 KB
    float* dinv    = (float*)ws;                  ws += (size_t)N_NODES * 4;       // 400 KB
    float* part    = (float*)ws;                  ws += (size_t)NBG * 256 * 4;     // 1.6 MB
    float* scale   = (float*)ws;                  ws += C * 4;
    float* shift   = (float*)ws;

    const int* src = edge;
    const int* dst = edge + N_EDGES;

    k_init     <<<C * C / 256,           256, 0, stream>>>(W, wt);
    k_coarse   <<<PB,                    256, 0, stream>>>(dst, blk_cnt);
    k_offsets  <<<NB_C,                  512, 0, stream>>>(blk_cnt, offset, total);
    k_cbase    <<<1,                     512, 0, stream>>>(total, cbase, offs);
    k_partition<<<PB,                    256, 0, stream>>>(src, dst, cbase, offset, pairs);
    k_fine     <<<NB_C,                  256, 0, stream>>>(pairs, cbase, x, dinv, offs, srt, xb);
    k_aggregate<<<N_NODES / 8,           256, 0, stream>>>((const ushort4*)xb, srt, offs, dinv, (unsigned long long*)agg);
    k_gemm     <<<NBG,                   256, 0, stream>>>(agg, wt, bias, out, part);
    k_params   <<<1,                    1024, 0, stream>>>(part, gamma, beta, scale, shift);
    k_apply    <<<N_NODES * C / 4 / 256, 256, 0, stream>>>(out, scale, shift);
}

// Round 10
// 242.052 us; speedup vs baseline: 1.0517x; 1.0517x over previous
//
#include <hip/hip_runtime.h>

#define N_NODES 100000
#define N_EDGES 1600000
#define C 128
#define LEAKY 0.01f
#define BN_EPS 1e-5f
#define NB_C 391           // coarse buckets (dst>>8), 256 nodes each
#define PB 391             // partition blocks
#define PBLK 4096          // edges per partition block
#define STASH 8192         // fine-kernel LDS pair stash (avg bucket = 4092)
#define NBG 1563           // gemm blocks = ceil(100000/64)

typedef __attribute__((ext_vector_type(8))) short short8;   // 8 bf16 = 16B
typedef __attribute__((ext_vector_type(4))) float f32x4;

__device__ __forceinline__ unsigned short f2bf(float f) {   // RNE float->bf16
    unsigned int u = __builtin_bit_cast(unsigned int, f);
    u += 0x7FFFu + ((u >> 16) & 1u);
    return (unsigned short)(u >> 16);
}
__device__ __forceinline__ float bf2f(unsigned short b) {
    unsigned int u = ((unsigned int)b) << 16;
    return __builtin_bit_cast(float, u);
}

// ---------------------------------------------------------------- init: cast-transpose W
__global__ __launch_bounds__(256) void k_init(const float* __restrict__ W,
                                              unsigned short* __restrict__ wt) {
    int i = blockIdx.x * 256 + threadIdx.x;
    wt[i] = f2bf(W[(i & 127) * C + (i >> 7)]);   // wt[c][k] = W[k][c]
}

// ---------------------------------------------------------------- coarse histogram: per-block counts per bucket
__global__ __launch_bounds__(256) void k_coarse(const int* __restrict__ dst,
                                                int* __restrict__ blk_cnt) {
    __shared__ int lh[NB_C];
    int tid = threadIdx.x, blk = blockIdx.x;
    for (int i = tid; i < NB_C; i += 256) lh[i] = 0;
    __syncthreads();
    #pragma unroll
    for (int it = 0; it < PBLK / 256; ++it) {
        int e = blk * PBLK + it * 256 + tid;
        if (e < N_EDGES) atomicAdd(&lh[dst[e] >> 8], 1);
    }
    __syncthreads();
    for (int i = tid; i < NB_C; i += 256) blk_cnt[i * PB + blk] = lh[i];
}

// ---------------------------------------------------------------- per-bucket exclusive scan over blocks
__global__ __launch_bounds__(512) void k_offsets(const int* __restrict__ blk_cnt,
                                                 int* __restrict__ offset,
                                                 int* __restrict__ total) {
    __shared__ int tmp[512];
    int t = threadIdx.x, k = blockIdx.x;
    int v = (t < PB) ? blk_cnt[k * PB + t] : 0;
    tmp[t] = v;
    __syncthreads();
    for (int off = 1; off < 512; off <<= 1) {
        int u = (t >= off) ? tmp[t - off] : 0;
        __syncthreads();
        tmp[t] += u;
        __syncthreads();
    }
    if (t < PB) offset[k * PB + t] = tmp[t] - v;
    if (t == 511) total[k] = tmp[511];
}

// ---------------------------------------------------------------- bucket-base scan (1 block)
__global__ __launch_bounds__(512) void k_cbase(const int* __restrict__ total,
                                               int* __restrict__ cbase,
                                               int* __restrict__ offs) {
    __shared__ int tmp[512];
    int t = threadIdx.x;
    int v = (t < NB_C) ? total[t] : 0;
    tmp[t] = v;
    __syncthreads();
    for (int off = 1; off < 512; off <<= 1) {
        int u = (t >= off) ? tmp[t - off] : 0;
        __syncthreads();
        tmp[t] += u;
        __syncthreads();
    }
    if (t < NB_C) cbase[t] = tmp[t] - v;
    if (t == 0) { cbase[NB_C] = N_EDGES; offs[N_NODES] = N_EDGES; }
}

// ---------------------------------------------------------------- partition: packed (src | dlow<<17) into bucket chunks
__global__ __launch_bounds__(256) void k_partition(const int* __restrict__ src,
                                                   const int* __restrict__ dst,
                                                   const int* __restrict__ cbase,
                                                   const int* __restrict__ offset,
                                                   unsigned int* __restrict__ pairs) {
    __shared__ int lh[NB_C];
    __shared__ int lbase[NB_C];
    int tid = threadIdx.x, blk = blockIdx.x;
    for (int i = tid; i < NB_C; i += 256) {
        lh[i] = 0;
        lbase[i] = cbase[i] + offset[i * PB + blk];
    }
    __syncthreads();
    #pragma unroll
    for (int it = 0; it < PBLK / 256; ++it) {
        int e = blk * PBLK + it * 256 + tid;
        if (e < N_EDGES) {
            int d = dst[e];
            int b = d >> 8;
            int r = atomicAdd(&lh[b], 1);
            pairs[lbase[b] + r] = (unsigned int)src[e] | ((unsigned int)(d & 255) << 17);
        }
    }
}

// ---------------------------------------------------------------- fine: per-bucket hist -> dinv+offs; LDS-rank -> srt
__global__ __launch_bounds__(256) void k_fine(const unsigned int* __restrict__ pairs,
                                              const int* __restrict__ cbase,
                                              float* __restrict__ dinv,
                                              int* __restrict__ offs,
                                              int* __restrict__ srt) {
    __shared__ int hist[256];
    __shared__ int loff[256];
    __shared__ int cnt2[256];
    __shared__ unsigned int stash[STASH];
    int tid = threadIdx.x, blk = blockIdx.x;
    int nbase = blk * 256;
    int nn = (nbase + 256 <= N_NODES) ? 256 : (N_NODES - nbase);
    int ebeg = cbase[blk];
    int ne = cbase[blk + 1] - ebeg;

    hist[tid] = 0; cnt2[tid] = 0;
    __syncthreads();
    for (int k = tid; k < ne; k += 256) {
        unsigned int pk = pairs[ebeg + k];
        if (k < STASH) stash[k] = pk;
        atomicAdd(&hist[pk >> 17], 1);
    }
    __syncthreads();
    if (tid < nn) dinv[nbase + tid] = rsqrtf((float)(hist[tid] + 1));
    // exclusive scan of hist into loff
    loff[tid] = hist[tid];
    __syncthreads();
    for (int off = 1; off < 256; off <<= 1) {
        int u = (tid >= off) ? loff[tid - off] : 0;
        __syncthreads();
        loff[tid] += u;
        __syncthreads();
    }
    loff[tid] -= hist[tid];           // exclusive
    if (tid < nn) offs[nbase + tid] = ebeg + loff[tid];
    __syncthreads();
    for (int k = tid; k < ne; k += 256) {
        unsigned int pk = (k < STASH) ? stash[k] : pairs[ebeg + k];
        int dl = pk >> 17;
        int r = atomicAdd(&cnt2[dl], 1);
        srt[ebeg + loff[dl] + r] = (int)(pk & 0x1FFFFu);
    }
}

// ---------------------------------------------------------------- cast: xb = bf16(x * dinv[row]), full grid
__global__ __launch_bounds__(256) void k_cast(const float* __restrict__ x,
                                              const float* __restrict__ dinv,
                                              unsigned short* __restrict__ xb) {
    int i = blockIdx.x * 256 + threadIdx.x;   // ushort8 index, N*C/8 total
    int node = i >> 4;                         // 16 ushort8 per row
    float dv = dinv[node];
    const float4* xp = (const float4*)(x) + (size_t)i * 2;
    float4 p0 = xp[0], p1 = xp[1];
    short8 o;
    o[0] = (short)f2bf(p0.x * dv); o[1] = (short)f2bf(p0.y * dv);
    o[2] = (short)f2bf(p0.z * dv); o[3] = (short)f2bf(p0.w * dv);
    o[4] = (short)f2bf(p1.x * dv); o[5] = (short)f2bf(p1.y * dv);
    o[6] = (short)f2bf(p1.z * dv); o[7] = (short)f2bf(p1.w * dv);
    ((short8*)xb)[i] = o;
}

// ---------------------------------------------------------------- aggregate: 16 lanes/node, short8/lane, masked 8-wide
// agg[d] = bf16( dn * (xb[d] + sum_bucket xb[s]) )
__global__ __launch_bounds__(256) void k_aggregate(const short8* __restrict__ xb8,
                                                   const int* __restrict__ srt,
                                                   const int* __restrict__ offs,
                                                   const float* __restrict__ dinv,
                                                   short8* __restrict__ agg8) {
    int node = blockIdx.x * 16 + (threadIdx.x >> 4);
    int c8 = threadIdx.x & 15;

    float dn = dinv[node];
    int beg = offs[node];
    int end = offs[node + 1];

    short8 ms = xb8[(size_t)node * 16 + c8];
    float ax[8];
    #pragma unroll
    for (int ch = 0; ch < 8; ++ch) ax[ch] = bf2f((unsigned short)ms[ch]);

    for (int k = beg; k < end; k += 8) {
        int   idx[8];
        float msk[8];
        #pragma unroll
        for (int i = 0; i < 8; ++i) {
            int ki = k + i;
            msk[i] = (ki < end) ? 1.0f : 0.0f;
            idx[i] = srt[(ki < end) ? ki : end - 1];
        }
        short8 m[8];
        #pragma unroll
        for (int i = 0; i < 8; ++i) m[i] = xb8[(size_t)idx[i] * 16 + c8];
        #pragma unroll
        for (int i = 0; i < 8; ++i)
            #pragma unroll
            for (int ch = 0; ch < 8; ++ch)
                ax[ch] += msk[i] * bf2f((unsigned short)m[i][ch]);
    }

    short8 o;
    #pragma unroll
    for (int ch = 0; ch < 8; ++ch) o[ch] = (short)f2bf(dn * ax[ch]);
    agg8[(size_t)node * 16 + c8] = o;
}

// ---------------------------------------------------------------- gemm: out = leaky(agg@W + bias), + BN partials
__global__ __launch_bounds__(256) void k_gemm(const unsigned short* __restrict__ agg,
                                              const unsigned short* __restrict__ wt,
                                              const float* __restrict__ bias,
                                              float* __restrict__ out,
                                              float* __restrict__ part) {
    __shared__ float lsum[C], lsq[C];
    for (int i = threadIdx.x; i < C; i += 256) { lsum[i] = 0.0f; lsq[i] = 0.0f; }
    __syncthreads();

    int tile = blockIdx.x * 4 + (threadIdx.x >> 6);
    int lane = threadIdx.x & 63;
    if (tile < N_NODES / 16) {
        int row0 = tile * 16;
        int ar = lane & 15;
        int kg = (lane >> 4) * 8;

        short8 a[4];
        #pragma unroll
        for (int kk = 0; kk < 4; ++kk)
            a[kk] = *(const short8*)&agg[(size_t)(row0 + ar) * C + kk * 32 + kg];

        int rb = (lane >> 4) * 4;
        #pragma unroll
        for (int ct = 0; ct < 8; ++ct) {
            f32x4 acc = {0.f, 0.f, 0.f, 0.f};
            #pragma unroll
            for (int kk = 0; kk < 4; ++kk) {
                short8 b = *(const short8*)&wt[(size_t)(ct * 16 + ar) * C + kk * 32 + kg];
                acc = __builtin_amdgcn_mfma_f32_16x16x32_bf16(a[kk], b, acc, 0, 0, 0);
            }
            int col = ct * 16 + ar;      // C/D: col=lane&15, row=(lane>>4)*4+r
            float bb = bias[col];
            float s = 0.0f, q = 0.0f;
            #pragma unroll
            for (int r = 0; r < 4; ++r) {
                float v = acc[r] + bb;
                v = v > 0.0f ? v : LEAKY * v;
                out[(size_t)(row0 + rb + r) * C + col] = v;
                s += v; q += v * v;
            }
            atomicAdd(&lsum[col], s);
            atomicAdd(&lsq[col], q);
        }
    }
    __syncthreads();
    for (int i = threadIdx.x; i < C; i += 256) {
        part[(size_t)blockIdx.x * 256 + i]       = lsum[i];
        part[(size_t)blockIdx.x * 256 + 128 + i] = lsq[i];
    }
}

// ---------------------------------------------------------------- params: reduce partials, fold BN scale/shift
__global__ __launch_bounds__(1024) void k_params(const float* __restrict__ part,
                                                 const float* __restrict__ gamma,
                                                 const float* __restrict__ beta,
                                                 float* __restrict__ scale,
                                                 float* __restrict__ shift) {
    __shared__ float rs[1024], rq[1024];
    int c = threadIdx.x & 127, g = threadIdx.x >> 7;   // 8 groups
    float s = 0.0f, q = 0.0f;
    for (int b = g; b < NBG; b += 8) {
        s += part[(size_t)b * 256 + c];
        q += part[(size_t)b * 256 + 128 + c];
    }
    rs[threadIdx.x] = s; rq[threadIdx.x] = q;
    __syncthreads();
    if (threadIdx.x < 128) {
        float S = 0.0f, Q = 0.0f;
        #pragma unroll
        for (int g2 = 0; g2 < 8; ++g2) { S += rs[g2 * 128 + c]; Q += rq[g2 * 128 + c]; }
        float inv_n = 1.0f / (float)N_NODES;
        float mean = S * inv_n;
        float var = Q * inv_n - mean * mean;
        float sc = gamma[c] * rsqrtf(var + BN_EPS);
        scale[c] = sc;
        shift[c] = beta[c] - mean * sc;
    }
}

// ---------------------------------------------------------------- apply: out = out*scale + shift (in place)
__global__ __launch_bounds__(256) void k_apply(float* __restrict__ out,
                                               const float* __restrict__ scale,
                                               const float* __restrict__ shift) {
    int i = blockIdx.x * 256 + threadIdx.x;  // float4 index, exactly N*C/4
    int c4 = i & 31;
    float4 v = ((float4*)out)[i];
    float4 sc = ((const float4*)scale)[c4];
    float4 sh = ((const float4*)shift)[c4];
    v.x = v.x * sc.x + sh.x;
    v.y = v.y * sc.y + sh.y;
    v.z = v.z * sc.z + sh.z;
    v.w = v.w * sc.w + sh.w;
    ((float4*)out)[i] = v;
}

extern "C" void kernel_launch(void* const* d_in, const int* in_sizes, int n_in,
                              void* d_out, int out_size, void* d_ws, size_t ws_size,
                              hipStream_t stream) {
    const float* x     = (const float*)d_in[0];
    const int*   edge  = (const int*)d_in[1];
    const float* W     = (const float*)d_in[2];
    const float* bias  = (const float*)d_in[3];
    const float* gamma = (const float*)d_in[4];
    const float* beta  = (const float*)d_in[5];
    float* out = (float*)d_out;
    char* ws = (char*)d_ws;

    // workspace layout (~68 MB)
    unsigned short* xb    = (unsigned short*)ws;  ws += (size_t)N_NODES * C * 2;   // 25.6 MB
    unsigned short* agg   = (unsigned short*)ws;  ws += (size_t)N_NODES * C * 2;   // 25.6 MB
    unsigned short* wt    = (unsigned short*)ws;  ws += (size_t)C * C * 2;         // 32 KB
    unsigned int*   pairs = (unsigned int*)ws;    ws += (size_t)N_EDGES * 4;       // 6.4 MB
    int*   srt     = (int*)ws;                    ws += (size_t)N_EDGES * 4;       // 6.4 MB
    int*   blk_cnt = (int*)ws;                    ws += (size_t)NB_C * PB * 4;     // 612 KB
    int*   offset  = (int*)ws;                    ws += (size_t)NB_C * PB * 4;     // 612 KB
    int*   total   = (int*)ws;                    ws += 512 * 4;
    int*   cbase   = (int*)ws;                    ws += 512 * 4;
    int*   offs    = (int*)ws;                    ws += (size_t)(N_NODES + 1) * 4; // 400 KB
    float* dinv    = (float*)ws;                  ws += (size_t)N_NODES * 4;       // 400 KB
    float* part    = (float*)ws;                  ws += (size_t)NBG * 256 * 4;     // 1.6 MB
    float* scale   = (float*)ws;                  ws += C * 4;
    float* shift   = (float*)ws;

    const int* src = edge;
    const int* dst = edge + N_EDGES;

    k_init     <<<C * C / 256,           256, 0, stream>>>(W, wt);
    k_coarse   <<<PB,                    256, 0, stream>>>(dst, blk_cnt);
    k_offsets  <<<NB_C,                  512, 0, stream>>>(blk_cnt, offset, total);
    k_cbase    <<<1,                     512, 0, stream>>>(total, cbase, offs);
    k_partition<<<PB,                    256, 0, stream>>>(src, dst, cbase, offset, pairs);
    k_fine     <<<NB_C,                  256, 0, stream>>>(pairs, cbase, dinv, offs, srt);
    k_cast     <<<N_NODES * C / 8 / 256, 256, 0, stream>>>(x, dinv, xb);
    k_aggregate<<<N_NODES / 16,          256, 0, stream>>>((const short8*)xb, srt, offs, dinv, (short8*)agg);
    k_gemm     <<<NBG,                   256, 0, stream>>>(agg, wt, bias, out, part);
    k_params   <<<1,                    1024, 0, stream>>>(part, gamma, beta, scale, shift);
    k_apply    <<<N_NODES * C / 4 / 256, 256, 0, stream>>>(out, scale, shift);
}